// Round 3
// baseline (631.322 us; speedup 1.0000x reference)
//
#include <hip/hip_runtime.h>
#include <hip/hip_bf16.h>

// Problem constants
constexpr int kB  = 1024;
constexpr int kV  = 6890;
constexpr int kJ  = 24;
constexpr int kNB = 10;
constexpr int kP  = 207;   // 23*9
constexpr int kH  = 17;

constexpr int kN   = kV * 3;      // 20670
constexpr int kKP  = 224;         // K padded: 207 pf + 10 betas + 1 vt + 6 zero
constexpr int kNT  = 1296;        // n-tiles of 16 (N_pad = 20736)
constexpr int kNP  = kNT * 16;    // 20736
constexpr int kVC  = 862;         // v-chunk for k_js part (8 chunks)
constexpr int kVCh = 1723;        // v-chunk for k_lbs (4 chunks: 3x1723 + 1721)
constexpr int kNVC = 4;

constexpr int kJsBlocks = kJ * 8;         // 192
constexpr int kPbBlocks = kNP / 64;       // 324

// Output layout (flat concat, FP32 elements)
constexpr size_t O_VERTS  = 0;
constexpr size_t O_JOINTS = (size_t)kB * kV * 3;              // 21166080
constexpr size_t O_ROT    = O_JOINTS + (size_t)kB * kJ * 3;   // 21239808
constexpr size_t O_JFV    = O_ROT + (size_t)kB * kJ * 9;      // 21460992

// Workspace layout (fp32 element offsets). Total ~11 MB (unchanged from r2).
constexpr size_t WS_JSP  = 0;                        // 24*8*33 = 6336 floats
constexpr size_t WS_A    = 8192;                     // kB*288  = 294912
constexpr size_t WS_ROOT = WS_A + (size_t)kB * 288;  // kB*3 (padded to 4096)
constexpr size_t WS_ASWZ = WS_ROOT + 4096;           // 1024*224 ushort = 114688 floats
constexpr size_t WS_BSWZ = WS_ASWZ + 114688;         // 1296*7*512 ushort

typedef __attribute__((ext_vector_type(8))) short short8;
typedef __attribute__((ext_vector_type(4))) float float4v;

__device__ __forceinline__ unsigned short f2bf(float f) {
    unsigned u = __float_as_uint(f);
    unsigned r = (u + 0x7FFFu + ((u >> 16) & 1u)) >> 16;  // RNE
    return (unsigned short)r;
}

// inline classifier: amb0 is lbs_weights iff its first 24 floats (one weight
// row) sum to ~1.  J_regressor's first 24 entries sum to ~0.003.
__device__ __forceinline__ bool amb0_is_weights(const float* __restrict__ amb0) {
    float s = 0.f;
    #pragma unroll
    for (int i = 0; i < kJ; i++) s += amb0[i];
    return fabsf(s - 1.0f) < 0.5f;
}

// swizzled-A element index for (batch b, k-row k); must match k_gemm's read:
// lane l of tile kt reads shorts [l*8 .. l*8+7] = (quad=l>>4, minr=l&15, kin=0..7)
__device__ __forceinline__ size_t a_idx(int mtile, int minr, int k) {
    int kt = k >> 5, quad = (k >> 3) & 3, kin = k & 7;
    return ((size_t)(mtile * 7 + kt)) * 512 + (size_t)(quad * 128 + minr * 8 + kin);
}

// ---------------------------------------------------------------------------
// k_sfb: fused front-end (independent work, one dispatch).
//   blocks [0, 192):    js partials  partial[(j*8+c)*33 + i] over v-chunk c
//   blocks [192, 516):  swizzled bf16 B (K_pad=224 x N_pad=20736)
// ---------------------------------------------------------------------------
__global__ __launch_bounds__(256) void k_sfb(
    const float* __restrict__ amb0,
    const float* __restrict__ amb1,
    const float* __restrict__ sd,
    const float* __restrict__ vt,
    const float* __restrict__ pd,
    float* __restrict__ partial,
    unsigned short* __restrict__ bswz)
{
    __shared__ unsigned short lds[kKP][68];
    __shared__ float red[4][33];

    int t = threadIdx.x;

    if (blockIdx.x < kJsBlocks) {
        // ----- js part -----
        const float* Jreg = amb0_is_weights(amb0) ? amb1 : amb0;
        int j = blockIdx.x >> 3;
        int c = blockIdx.x & 7;
        int lane = t & 63;
        int wave = t >> 6;

        float acc[33];
        #pragma unroll
        for (int i = 0; i < 33; i++) acc[i] = 0.f;

        int vend = min(kVC * (c + 1), kV);
        for (int v = kVC * c + t; v < vend; v += 256) {
            float w = Jreg[j * kV + v];
            const float* sdp = sd + (size_t)v * 30;
            #pragma unroll
            for (int k = 0; k < 3; k++) {
                #pragma unroll
                for (int l = 0; l < kNB; l++)
                    acc[k * 11 + l] += w * sdp[k * 10 + l];
                acc[k * 11 + 10] += w * vt[v * 3 + k];
            }
        }
        #pragma unroll
        for (int off = 32; off > 0; off >>= 1) {
            #pragma unroll
            for (int i = 0; i < 33; i++)
                acc[i] += __shfl_down(acc[i], off, 64);
        }
        if (lane == 0) {
            #pragma unroll
            for (int i = 0; i < 33; i++) red[wave][i] = acc[i];
        }
        __syncthreads();
        if (t < 33) {
            float s = red[0][t] + red[1][t] + red[2][t] + red[3][t];
            partial[((size_t)j * 8 + c) * 33 + t] = s;
        }
    } else {
        // ----- prep_b part -----
        int g = blockIdx.x - kJsBlocks;
        int n0 = g * 64;

        for (int kbase = 0; kbase < kKP; kbase += 4) {
            int k = kbase + (t >> 6);
            int nl = t & 63;
            int n = n0 + nl;
            float val = 0.f;
            if (n < kN) {
                if (k < kP)                 val = pd[(size_t)k * kN + n];
                else if (k < kP + kNB)      val = sd[(size_t)n * kNB + (k - kP)];
                else if (k == kP + kNB)     val = vt[n];
            }
            lds[k][nl] = f2bf(val);
        }
        __syncthreads();

        #pragma unroll 1
        for (int tt = 0; tt < 4; tt++) {
            int ntile = g * 4 + tt;
            #pragma unroll 1
            for (int kt = 0; kt < 7; kt++) {
                size_t base = ((size_t)ntile * 7 + kt) * 512;
                #pragma unroll
                for (int u = 0; u < 2; u++) {
                    int e = t * 2 + u;
                    int quad = e >> 7, rem = e & 127;
                    int nin = rem >> 3, kin = rem & 7;
                    int k = kt * 32 + quad * 8 + kin;
                    bswz[base + e] = lds[k][tt * 16 + nin];
                }
            }
        }
    }
}

// ---------------------------------------------------------------------------
// k_pose: per-batch rodrigues + FK chain + A matrices.
// Also zeroes this batch's JFV output slot (k_lbs atomicAdds partials there).
// ---------------------------------------------------------------------------
__global__ __launch_bounds__(64) void k_pose(
    const float* __restrict__ pose,
    const float* __restrict__ betas,
    const float* __restrict__ gor,
    const float* __restrict__ jsp,
    float* __restrict__ wsA,
    float* __restrict__ wsRoot,
    unsigned short* __restrict__ aswz,
    float* __restrict__ out)
{
    __shared__ float Rsh[kJ][9];
    __shared__ float Jr[kJ][3];
    __shared__ float G[kJ][12];

    int b = blockIdx.x;
    int t = threadIdx.x;
    int mtile = b >> 4, minr = b & 15;

    if (t < 51) out[O_JFV + (size_t)b * 51 + t] = 0.f;   // jfv accumulator init

    if (t < kJ) {
        float rx, ry, rz;
        if (t == 0) {
            rx = gor[b * 3 + 0]; ry = gor[b * 3 + 1]; rz = gor[b * 3 + 2];
        } else {
            int o = b * 69 + (t - 1) * 3;
            rx = pose[o]; ry = pose[o + 1]; rz = pose[o + 2];
        }
        float ex = rx + 1e-8f, ey = ry + 1e-8f, ez = rz + 1e-8f;
        float ang = sqrtf(ex * ex + ey * ey + ez * ez);
        float x = rx / ang, y = ry / ang, z = rz / ang;
        float s = sinf(ang), c = cosf(ang), oc = 1.0f - c;
        float r[9];
        r[0] = 1.0f - oc * (y * y + z * z);
        r[1] = -s * z + oc * (x * y);
        r[2] =  s * y + oc * (x * z);
        r[3] =  s * z + oc * (x * y);
        r[4] = 1.0f - oc * (x * x + z * z);
        r[5] = -s * x + oc * (y * z);
        r[6] = -s * y + oc * (x * z);
        r[7] =  s * x + oc * (y * z);
        r[8] = 1.0f - oc * (x * x + y * y);
        #pragma unroll
        for (int i = 0; i < 9; i++) Rsh[t][i] = r[i];
        float* ro = out + O_ROT + (size_t)b * (kJ * 9) + (size_t)t * 9;
        #pragma unroll
        for (int i = 0; i < 9; i++) ro[i] = r[i];
        if (t >= 1) {
            // pose-feature rows 0..206 of swizzled A, bf16
            #pragma unroll
            for (int i = 0; i < 9; i++) {
                int k = (t - 1) * 9 + i;
                float val = r[i] - ((i == 0 || i == 4 || i == 8) ? 1.0f : 0.0f);
                aswz[a_idx(mtile, minr, k)] = f2bf(val);
            }
        }
        // Jr = (reduced js partials) dot [betas | 1]
        float bt[kNB];
        #pragma unroll
        for (int l = 0; l < kNB; l++) bt[l] = betas[b * kNB + l];
        #pragma unroll
        for (int k2 = 0; k2 < 3; k2++) {
            float row[11];
            #pragma unroll
            for (int i = 0; i < 11; i++) row[i] = 0.f;
            #pragma unroll
            for (int c8 = 0; c8 < 8; c8++) {
                const float* pp = jsp + ((size_t)t * 8 + c8) * 33 + k2 * 11;
                #pragma unroll
                for (int i = 0; i < 11; i++) row[i] += pp[i];
            }
            float acc = row[10];
            #pragma unroll
            for (int l = 0; l < kNB; l++) acc += bt[l] * row[l];
            Jr[t][k2] = acc;
        }
    } else if (t < 41 + kJ) {
        // rows 207..223 of swizzled A: betas | 1.0 | zero pad (17 rows)
        int idx = t - kJ;
        if (idx < 17) {
            int k = kP + idx;
            float val = 0.f;
            if (idx < kNB)          val = betas[b * kNB + idx];
            else if (k == kP + kNB) val = 1.0f;
            aswz[a_idx(mtile, minr, k)] = f2bf(val);
        }
    }
    __syncthreads();

    if (t == 0) {
        const int par[kJ] = {-1,0,0,0,1,2,3,4,5,6,7,8,9,9,9,12,13,14,16,17,18,19,20,21};
        #pragma unroll
        for (int m = 0; m < 3; m++) {
            #pragma unroll
            for (int n = 0; n < 3; n++) G[0][m * 4 + n] = Rsh[0][m * 3 + n];
            G[0][m * 4 + 3] = Jr[0][m];
        }
        for (int i = 1; i < kJ; i++) {
            int p = par[i];
            float rel[3];
            #pragma unroll
            for (int k = 0; k < 3; k++) rel[k] = Jr[i][k] - Jr[p][k];
            #pragma unroll
            for (int m = 0; m < 3; m++) {
                float g0 = G[p][m * 4 + 0], g1 = G[p][m * 4 + 1], g2 = G[p][m * 4 + 2];
                #pragma unroll
                for (int n = 0; n < 3; n++) {
                    G[i][m * 4 + n] = g0 * Rsh[i][0 * 3 + n]
                                    + g1 * Rsh[i][1 * 3 + n]
                                    + g2 * Rsh[i][2 * 3 + n];
                }
                G[i][m * 4 + 3] = g0 * rel[0] + g1 * rel[1] + g2 * rel[2]
                                + G[p][m * 4 + 3];
            }
        }
    }
    __syncthreads();

    if (t < kJ) {
        float* Aj = wsA + (size_t)b * 288 + (size_t)t * 12;
        float* jo = out + O_JOINTS + (size_t)b * (kJ * 3) + (size_t)t * 3;
        #pragma unroll
        for (int m = 0; m < 3; m++) {
            float g0 = G[t][m * 4 + 0], g1 = G[t][m * 4 + 1], g2 = G[t][m * 4 + 2];
            Aj[m * 4 + 0] = g0;
            Aj[m * 4 + 1] = g1;
            Aj[m * 4 + 2] = g2;
            Aj[m * 4 + 3] = G[t][m * 4 + 3]
                          - (g0 * Jr[t][0] + g1 * Jr[t][1] + g2 * Jr[t][2]);
            jo[m] = G[t][m * 4 + 3] - G[0][m * 4 + 3];
        }
        if (t == 0) {
            #pragma unroll
            for (int k = 0; k < 3; k++) wsRoot[b * 3 + k] = G[0][k * 4 + 3];
        }
    }
}

// ---------------------------------------------------------------------------
// k_gemm: v_posed[b][n] = A(1024x224) @ B(224x20670) -> out[O_VERTS] (fp32).
// ---------------------------------------------------------------------------
__global__ __launch_bounds__(256) void k_gemm(
    const unsigned short* __restrict__ A,
    const unsigned short* __restrict__ B,
    float* __restrict__ out)
{
    int tid = threadIdx.x;
    int lane = tid & 63;
    int wid = tid >> 6;
    int m0t = blockIdx.y * 8 + (wid >> 1) * 4;
    int n0t = blockIdx.x * 8 + (wid & 1) * 4;

    float4v acc[4][4];
    #pragma unroll
    for (int i = 0; i < 4; i++)
        #pragma unroll
        for (int j = 0; j < 4; j++)
            acc[i][j] = (float4v){0.f, 0.f, 0.f, 0.f};

    #pragma unroll
    for (int kt = 0; kt < 7; kt++) {
        short8 a[4], b[4];
        #pragma unroll
        for (int i = 0; i < 4; i++)
            a[i] = *(const short8*)(A + ((size_t)(m0t + i) * 7 + kt) * 512 + lane * 8);
        #pragma unroll
        for (int j = 0; j < 4; j++)
            b[j] = *(const short8*)(B + ((size_t)(n0t + j) * 7 + kt) * 512 + lane * 8);
        #pragma unroll
        for (int i = 0; i < 4; i++)
            #pragma unroll
            for (int j = 0; j < 4; j++)
                acc[i][j] = __builtin_amdgcn_mfma_f32_16x16x32_bf16(
                    a[i], b[j], acc[i][j], 0, 0, 0);
    }

    int rbase = (lane >> 4) * 4;
    int col = lane & 15;
    #pragma unroll
    for (int i = 0; i < 4; i++) {
        #pragma unroll
        for (int j = 0; j < 4; j++) {
            int n = (n0t + j) * 16 + col;
            if (n < kN) {
                #pragma unroll
                for (int reg = 0; reg < 4; reg++) {
                    int brow = (m0t + i) * 16 + rbase + reg;
                    out[O_VERTS + (size_t)brow * kN + n] = acc[i][j][reg];
                }
            }
        }
    }
}

// ---------------------------------------------------------------------------
// k_lbs: fused LBS apply + jfv partial accumulation.
// Grid (512 bpairs x 4 vchunks) = 2048 blocks -> 8 blocks-worth/CU, ~4 waves
// resident/SIMD (VGPR<=128 via launch_bounds) -- fixes the measured 21%
// occupancy that left the A-panel load chains exposed (r2: 285us, VALU 57%).
// Per-chunk jfv partials are atomicAdd'ed into out[O_JFV] (zeroed by k_pose);
// k_fin does the root17 subtraction afterwards.
// ---------------------------------------------------------------------------
__global__ __launch_bounds__(256, 4) void k_lbs(
    const float* __restrict__ amb0,
    const float* __restrict__ amb1,
    const float* __restrict__ Jh,
    const float* __restrict__ wsA,
    const float* __restrict__ wsRoot,
    float* __restrict__ out)
{
    const float* W = amb0_is_weights(amb0) ? amb0 : amb1;

    int t = threadIdx.x;
    int b0 = blockIdx.x * 2;
    int v0 = blockIdx.y * kVCh;
    int vend = min(v0 + kVCh, kV);

    const float4v* A04 = (const float4v*)(wsA + (size_t)b0 * 288);  // uniform
    const float4v* A14 = A04 + 72;
    float r00 = wsRoot[(size_t)b0 * 3 + 0];
    float r01 = wsRoot[(size_t)b0 * 3 + 1];
    float r02 = wsRoot[(size_t)b0 * 3 + 2];
    float r10 = wsRoot[(size_t)b0 * 3 + 3];
    float r11 = wsRoot[(size_t)b0 * 3 + 4];
    float r12 = wsRoot[(size_t)b0 * 3 + 5];

    float acc[2][kH * 3];
    #pragma unroll
    for (int tb = 0; tb < 2; tb++)
        #pragma unroll
        for (int i = 0; i < kH * 3; i++) acc[tb][i] = 0.f;

    for (int v = v0 + t; v < vend; v += 256) {
        const float4v* Wv4 = (const float4v*)(W + (size_t)v * kJ);  // 16B-aligned
        float4v wv[6];
        #pragma unroll
        for (int q = 0; q < 6; q++) wv[q] = Wv4[q];

        float o[2][3];
        #pragma unroll
        for (int tb = 0; tb < 2; tb++) {
            const float4v* A4 = (tb == 0) ? A04 : A14;
            float T0[4] = {0.f, 0.f, 0.f, 0.f};
            float T1[4] = {0.f, 0.f, 0.f, 0.f};
            float T2[4] = {0.f, 0.f, 0.f, 0.f};
            #pragma unroll
            for (int j = 0; j < kJ; j++) {
                float wj = wv[j >> 2][j & 3];
                float4v a0 = A4[j * 3 + 0];
                float4v a1 = A4[j * 3 + 1];
                float4v a2 = A4[j * 3 + 2];
                #pragma unroll
                for (int q = 0; q < 4; q++) {
                    T0[q] += wj * a0[q];
                    T1[q] += wj * a1[q];
                    T2[q] += wj * a2[q];
                }
            }
            float rr0 = (tb == 0) ? r00 : r10;
            float rr1 = (tb == 0) ? r01 : r11;
            float rr2 = (tb == 0) ? r02 : r12;
            float* op = out + O_VERTS + ((size_t)(b0 + tb) * kV + v) * 3;
            float x = op[0], y = op[1], z = op[2];
            float o0 = T0[0] * x + T0[1] * y + T0[2] * z + T0[3] - rr0;
            float o1 = T1[0] * x + T1[1] * y + T1[2] * z + T1[3] - rr1;
            float o2 = T2[0] * x + T2[1] * y + T2[2] * z + T2[3] - rr2;
            op[0] = o0;
            op[1] = o1;
            op[2] = o2;
            o[tb][0] = o0; o[tb][1] = o1; o[tb][2] = o2;
        }
        // jfv accumulation (Jh is j-major -> coalesced dword loads)
        #pragma unroll
        for (int j = 0; j < kH; j++) {
            float wj = Jh[(size_t)j * kV + v];
            #pragma unroll
            for (int tb = 0; tb < 2; tb++) {
                acc[tb][j * 3 + 0] += wj * o[tb][0];
                acc[tb][j * 3 + 1] += wj * o[tb][1];
                acc[tb][j * 3 + 2] += wj * o[tb][2];
            }
        }
    }

    // reduce 2x51 partials: wave shuffle -> LDS cross-wave -> atomic into out
    #pragma unroll
    for (int off = 32; off > 0; off >>= 1) {
        #pragma unroll
        for (int tb = 0; tb < 2; tb++)
            #pragma unroll
            for (int i = 0; i < kH * 3; i++)
                acc[tb][i] += __shfl_down(acc[tb][i], off, 64);
    }
    __shared__ float red[4][2 * kH * 3];
    int lane = t & 63, wave = t >> 6;
    if (lane == 0) {
        #pragma unroll
        for (int tb = 0; tb < 2; tb++)
            #pragma unroll
            for (int i = 0; i < kH * 3; i++)
                red[wave][tb * (kH * 3) + i] = acc[tb][i];
    }
    __syncthreads();
    if (t < 2 * kH * 3) {
        float s = red[0][t] + red[1][t] + red[2][t] + red[3][t];
        int tb = t / (kH * 3);
        int i = t - tb * (kH * 3);
        atomicAdd(&out[O_JFV + (size_t)(b0 + tb) * 51 + i], s);
    }
}

// ---------------------------------------------------------------------------
// k_fin: in-place root17 subtraction on the accumulated jfv sums.
// S = Jh @ (verts - root) = jfv - root (Jh rows sum to 1);
// out = S_i - S_{i%3} = jfv_i - jfv_{0,k} = jfv - root17.   One wave per b.
// ---------------------------------------------------------------------------
__global__ __launch_bounds__(64) void k_fin(float* __restrict__ out)
{
    int b = blockIdx.x;
    int t = threadIdx.x;
    float si = 0.f, sk = 0.f;
    if (t < 51) {
        si = out[O_JFV + (size_t)b * 51 + t];
        sk = out[O_JFV + (size_t)b * 51 + (t % 3)];
    }
    __syncthreads();
    if (t < 51) out[O_JFV + (size_t)b * 51 + t] = si - sk;
}

extern "C" void kernel_launch(void* const* d_in, const int* in_sizes, int n_in,
                              void* d_out, int out_size, void* d_ws, size_t ws_size,
                              hipStream_t stream) {
    const float *pose = nullptr, *betas = nullptr, *gor = nullptr, *vt = nullptr,
                *sd = nullptr, *pd = nullptr, *Jh = nullptr;
    const float *amb0 = nullptr, *amb1 = nullptr;
    for (int i = 0; i < n_in; i++) {
        const float* p = (const float*)d_in[i];
        switch (in_sizes[i]) {
            case 70656:   pose  = p; break;
            case 10240:   betas = p; break;
            case 3072:    gor   = p; break;
            case 20670:   vt    = p; break;
            case 206700:  sd    = p; break;
            case 4278690: pd    = p; break;
            case 117130:  Jh    = p; break;
            case 165360:  if (!amb0) amb0 = p; else amb1 = p; break;
            default: break;
        }
    }

    float* ws = (float*)d_ws;
    float* jsp     = ws + WS_JSP;
    float* wsA     = ws + WS_A;
    float* wsRoot  = ws + WS_ROOT;
    unsigned short* aswz = (unsigned short*)(ws + WS_ASWZ);
    unsigned short* bswz = (unsigned short*)(ws + WS_BSWZ);

    float* out = (float*)d_out;

    k_sfb  <<<dim3(kJsBlocks + kPbBlocks), dim3(256), 0, stream>>>(
        amb0, amb1, sd, vt, pd, jsp, bswz);
    k_pose <<<dim3(kB),                 dim3(64),  0, stream>>>(
        pose, betas, gor, jsp, wsA, wsRoot, aswz, out);
    k_gemm <<<dim3(kNT / 8, kB / 128),  dim3(256), 0, stream>>>(aswz, bswz, out);
    k_lbs  <<<dim3(kB / 2, kNVC),       dim3(256), 0, stream>>>(
        amb0, amb1, Jh, wsA, wsRoot, out);
    k_fin  <<<dim3(kB),                 dim3(64),  0, stream>>>(out);
}

// Round 4
// 507.473 us; speedup vs baseline: 1.2440x; 1.2440x over previous
//
#include <hip/hip_runtime.h>
#include <hip/hip_bf16.h>

// Problem constants
constexpr int kB  = 1024;
constexpr int kV  = 6890;
constexpr int kJ  = 24;
constexpr int kNB = 10;
constexpr int kP  = 207;   // 23*9
constexpr int kH  = 17;

constexpr int kN   = kV * 3;      // 20670
constexpr int kKP  = 224;         // K padded: 207 pf + 10 betas + 1 vt + 6 zero
constexpr int kNT  = 1296;        // n-tiles of 16 (N_pad = 20736)
constexpr int kNP  = kNT * 16;    // 20736
constexpr int kVC  = 862;         // v-chunk for k_js part (8 chunks)
constexpr int kVCh = 1723;        // v-chunk for k_lbs (4 chunks: 3x1723 + 1721)
constexpr int kNVC = 4;

constexpr int kJsBlocks = kJ * 8;         // 192
constexpr int kPbBlocks = kNP / 64;       // 324

// Output layout (flat concat, FP32 elements)
constexpr size_t O_VERTS  = 0;
constexpr size_t O_JOINTS = (size_t)kB * kV * 3;              // 21166080
constexpr size_t O_ROT    = O_JOINTS + (size_t)kB * kJ * 3;   // 21239808
constexpr size_t O_JFV    = O_ROT + (size_t)kB * kJ * 9;      // 21460992

// Workspace layout (fp32 element offsets). Total ~11 MB.
constexpr size_t WS_JSP  = 0;                        // 24*8*33 = 6336 floats
constexpr size_t WS_A    = 8192;                     // kB*288  = 294912
constexpr size_t WS_ROOT = WS_A + (size_t)kB * 288;  // kB*3 (padded to 4096)
constexpr size_t WS_ASWZ = WS_ROOT + 4096;           // 1024*224 ushort = 114688 floats
constexpr size_t WS_BSWZ = WS_ASWZ + 114688;         // 1296*7*512 ushort

typedef __attribute__((ext_vector_type(8))) short short8;
typedef __attribute__((ext_vector_type(4))) float float4v;

__device__ __forceinline__ unsigned short f2bf(float f) {
    unsigned u = __float_as_uint(f);
    unsigned r = (u + 0x7FFFu + ((u >> 16) & 1u)) >> 16;  // RNE
    return (unsigned short)r;
}

// inline classifier: amb0 is lbs_weights iff its first 24 floats (one weight
// row) sum to ~1.  J_regressor's first 24 entries sum to ~0.003.
__device__ __forceinline__ bool amb0_is_weights(const float* __restrict__ amb0) {
    float s = 0.f;
    #pragma unroll
    for (int i = 0; i < kJ; i++) s += amb0[i];
    return fabsf(s - 1.0f) < 0.5f;
}

// swizzled-A element index for (batch b, k-row k); must match k_gemm's read:
// lane l of tile kt reads shorts [l*8 .. l*8+7] = (quad=l>>4, minr=l&15, kin=0..7)
__device__ __forceinline__ size_t a_idx(int mtile, int minr, int k) {
    int kt = k >> 5, quad = (k >> 3) & 3, kin = k & 7;
    return ((size_t)(mtile * 7 + kt)) * 512 + (size_t)(quad * 128 + minr * 8 + kin);
}

// ---------------------------------------------------------------------------
// k_sfb: fused front-end (independent work, one dispatch).
//   blocks [0, 192):    js partials  partial[(j*8+c)*33 + i] over v-chunk c
//   blocks [192, 516):  swizzled bf16 B (K_pad=224 x N_pad=20736)
// ---------------------------------------------------------------------------
__global__ __launch_bounds__(256) void k_sfb(
    const float* __restrict__ amb0,
    const float* __restrict__ amb1,
    const float* __restrict__ sd,
    const float* __restrict__ vt,
    const float* __restrict__ pd,
    float* __restrict__ partial,
    unsigned short* __restrict__ bswz)
{
    __shared__ unsigned short lds[kKP][68];
    __shared__ float red[4][33];

    int t = threadIdx.x;

    if (blockIdx.x < kJsBlocks) {
        // ----- js part -----
        const float* Jreg = amb0_is_weights(amb0) ? amb1 : amb0;
        int j = blockIdx.x >> 3;
        int c = blockIdx.x & 7;
        int lane = t & 63;
        int wave = t >> 6;

        float acc[33];
        #pragma unroll
        for (int i = 0; i < 33; i++) acc[i] = 0.f;

        int vend = min(kVC * (c + 1), kV);
        for (int v = kVC * c + t; v < vend; v += 256) {
            float w = Jreg[j * kV + v];
            const float* sdp = sd + (size_t)v * 30;
            #pragma unroll
            for (int k = 0; k < 3; k++) {
                #pragma unroll
                for (int l = 0; l < kNB; l++)
                    acc[k * 11 + l] += w * sdp[k * 10 + l];
                acc[k * 11 + 10] += w * vt[v * 3 + k];
            }
        }
        #pragma unroll
        for (int off = 32; off > 0; off >>= 1) {
            #pragma unroll
            for (int i = 0; i < 33; i++)
                acc[i] += __shfl_down(acc[i], off, 64);
        }
        if (lane == 0) {
            #pragma unroll
            for (int i = 0; i < 33; i++) red[wave][i] = acc[i];
        }
        __syncthreads();
        if (t < 33) {
            float s = red[0][t] + red[1][t] + red[2][t] + red[3][t];
            partial[((size_t)j * 8 + c) * 33 + t] = s;
        }
    } else {
        // ----- prep_b part -----
        int g = blockIdx.x - kJsBlocks;
        int n0 = g * 64;

        for (int kbase = 0; kbase < kKP; kbase += 4) {
            int k = kbase + (t >> 6);
            int nl = t & 63;
            int n = n0 + nl;
            float val = 0.f;
            if (n < kN) {
                if (k < kP)                 val = pd[(size_t)k * kN + n];
                else if (k < kP + kNB)      val = sd[(size_t)n * kNB + (k - kP)];
                else if (k == kP + kNB)     val = vt[n];
            }
            lds[k][nl] = f2bf(val);
        }
        __syncthreads();

        #pragma unroll 1
        for (int tt = 0; tt < 4; tt++) {
            int ntile = g * 4 + tt;
            #pragma unroll 1
            for (int kt = 0; kt < 7; kt++) {
                size_t base = ((size_t)ntile * 7 + kt) * 512;
                #pragma unroll
                for (int u = 0; u < 2; u++) {
                    int e = t * 2 + u;
                    int quad = e >> 7, rem = e & 127;
                    int nin = rem >> 3, kin = rem & 7;
                    int k = kt * 32 + quad * 8 + kin;
                    bswz[base + e] = lds[k][tt * 16 + nin];
                }
            }
        }
    }
}

// ---------------------------------------------------------------------------
// k_pose: per-batch rodrigues + FK chain + A matrices.
// Also zeroes this batch's JFV output slot (k_lbs atomicAdds partials there).
// ---------------------------------------------------------------------------
__global__ __launch_bounds__(64) void k_pose(
    const float* __restrict__ pose,
    const float* __restrict__ betas,
    const float* __restrict__ gor,
    const float* __restrict__ jsp,
    float* __restrict__ wsA,
    float* __restrict__ wsRoot,
    unsigned short* __restrict__ aswz,
    float* __restrict__ out)
{
    __shared__ float Rsh[kJ][9];
    __shared__ float Jr[kJ][3];
    __shared__ float G[kJ][12];

    int b = blockIdx.x;
    int t = threadIdx.x;
    int mtile = b >> 4, minr = b & 15;

    if (t < 51) out[O_JFV + (size_t)b * 51 + t] = 0.f;   // jfv accumulator init

    if (t < kJ) {
        float rx, ry, rz;
        if (t == 0) {
            rx = gor[b * 3 + 0]; ry = gor[b * 3 + 1]; rz = gor[b * 3 + 2];
        } else {
            int o = b * 69 + (t - 1) * 3;
            rx = pose[o]; ry = pose[o + 1]; rz = pose[o + 2];
        }
        float ex = rx + 1e-8f, ey = ry + 1e-8f, ez = rz + 1e-8f;
        float ang = sqrtf(ex * ex + ey * ey + ez * ez);
        float x = rx / ang, y = ry / ang, z = rz / ang;
        float s = sinf(ang), c = cosf(ang), oc = 1.0f - c;
        float r[9];
        r[0] = 1.0f - oc * (y * y + z * z);
        r[1] = -s * z + oc * (x * y);
        r[2] =  s * y + oc * (x * z);
        r[3] =  s * z + oc * (x * y);
        r[4] = 1.0f - oc * (x * x + z * z);
        r[5] = -s * x + oc * (y * z);
        r[6] = -s * y + oc * (x * z);
        r[7] =  s * x + oc * (y * z);
        r[8] = 1.0f - oc * (x * x + y * y);
        #pragma unroll
        for (int i = 0; i < 9; i++) Rsh[t][i] = r[i];
        float* ro = out + O_ROT + (size_t)b * (kJ * 9) + (size_t)t * 9;
        #pragma unroll
        for (int i = 0; i < 9; i++) ro[i] = r[i];
        if (t >= 1) {
            // pose-feature rows 0..206 of swizzled A, bf16
            #pragma unroll
            for (int i = 0; i < 9; i++) {
                int k = (t - 1) * 9 + i;
                float val = r[i] - ((i == 0 || i == 4 || i == 8) ? 1.0f : 0.0f);
                aswz[a_idx(mtile, minr, k)] = f2bf(val);
            }
        }
        // Jr = (reduced js partials) dot [betas | 1]
        float bt[kNB];
        #pragma unroll
        for (int l = 0; l < kNB; l++) bt[l] = betas[b * kNB + l];
        #pragma unroll
        for (int k2 = 0; k2 < 3; k2++) {
            float row[11];
            #pragma unroll
            for (int i = 0; i < 11; i++) row[i] = 0.f;
            #pragma unroll
            for (int c8 = 0; c8 < 8; c8++) {
                const float* pp = jsp + ((size_t)t * 8 + c8) * 33 + k2 * 11;
                #pragma unroll
                for (int i = 0; i < 11; i++) row[i] += pp[i];
            }
            float acc = row[10];
            #pragma unroll
            for (int l = 0; l < kNB; l++) acc += bt[l] * row[l];
            Jr[t][k2] = acc;
        }
    } else if (t < 41 + kJ) {
        // rows 207..223 of swizzled A: betas | 1.0 | zero pad (17 rows)
        int idx = t - kJ;
        if (idx < 17) {
            int k = kP + idx;
            float val = 0.f;
            if (idx < kNB)          val = betas[b * kNB + idx];
            else if (k == kP + kNB) val = 1.0f;
            aswz[a_idx(mtile, minr, k)] = f2bf(val);
        }
    }
    __syncthreads();

    if (t == 0) {
        const int par[kJ] = {-1,0,0,0,1,2,3,4,5,6,7,8,9,9,9,12,13,14,16,17,18,19,20,21};
        #pragma unroll
        for (int m = 0; m < 3; m++) {
            #pragma unroll
            for (int n = 0; n < 3; n++) G[0][m * 4 + n] = Rsh[0][m * 3 + n];
            G[0][m * 4 + 3] = Jr[0][m];
        }
        for (int i = 1; i < kJ; i++) {
            int p = par[i];
            float rel[3];
            #pragma unroll
            for (int k = 0; k < 3; k++) rel[k] = Jr[i][k] - Jr[p][k];
            #pragma unroll
            for (int m = 0; m < 3; m++) {
                float g0 = G[p][m * 4 + 0], g1 = G[p][m * 4 + 1], g2 = G[p][m * 4 + 2];
                #pragma unroll
                for (int n = 0; n < 3; n++) {
                    G[i][m * 4 + n] = g0 * Rsh[i][0 * 3 + n]
                                    + g1 * Rsh[i][1 * 3 + n]
                                    + g2 * Rsh[i][2 * 3 + n];
                }
                G[i][m * 4 + 3] = g0 * rel[0] + g1 * rel[1] + g2 * rel[2]
                                + G[p][m * 4 + 3];
            }
        }
    }
    __syncthreads();

    if (t < kJ) {
        float* Aj = wsA + (size_t)b * 288 + (size_t)t * 12;
        float* jo = out + O_JOINTS + (size_t)b * (kJ * 3) + (size_t)t * 3;
        #pragma unroll
        for (int m = 0; m < 3; m++) {
            float g0 = G[t][m * 4 + 0], g1 = G[t][m * 4 + 1], g2 = G[t][m * 4 + 2];
            Aj[m * 4 + 0] = g0;
            Aj[m * 4 + 1] = g1;
            Aj[m * 4 + 2] = g2;
            Aj[m * 4 + 3] = G[t][m * 4 + 3]
                          - (g0 * Jr[t][0] + g1 * Jr[t][1] + g2 * Jr[t][2]);
            jo[m] = G[t][m * 4 + 3] - G[0][m * 4 + 3];
        }
        if (t == 0) {
            #pragma unroll
            for (int k = 0; k < 3; k++) wsRoot[b * 3 + k] = G[0][k * 4 + 3];
        }
    }
}

// ---------------------------------------------------------------------------
// k_gemm: v_posed[b][n] = A(1024x224) @ B(224x20670) -> out[O_VERTS] (fp32).
// ---------------------------------------------------------------------------
__global__ __launch_bounds__(256) void k_gemm(
    const unsigned short* __restrict__ A,
    const unsigned short* __restrict__ B,
    float* __restrict__ out)
{
    int tid = threadIdx.x;
    int lane = tid & 63;
    int wid = tid >> 6;
    int m0t = blockIdx.y * 8 + (wid >> 1) * 4;
    int n0t = blockIdx.x * 8 + (wid & 1) * 4;

    float4v acc[4][4];
    #pragma unroll
    for (int i = 0; i < 4; i++)
        #pragma unroll
        for (int j = 0; j < 4; j++)
            acc[i][j] = (float4v){0.f, 0.f, 0.f, 0.f};

    #pragma unroll
    for (int kt = 0; kt < 7; kt++) {
        short8 a[4], b[4];
        #pragma unroll
        for (int i = 0; i < 4; i++)
            a[i] = *(const short8*)(A + ((size_t)(m0t + i) * 7 + kt) * 512 + lane * 8);
        #pragma unroll
        for (int j = 0; j < 4; j++)
            b[j] = *(const short8*)(B + ((size_t)(n0t + j) * 7 + kt) * 512 + lane * 8);
        #pragma unroll
        for (int i = 0; i < 4; i++)
            #pragma unroll
            for (int j = 0; j < 4; j++)
                acc[i][j] = __builtin_amdgcn_mfma_f32_16x16x32_bf16(
                    a[i], b[j], acc[i][j], 0, 0, 0);
    }

    int rbase = (lane >> 4) * 4;
    int col = lane & 15;
    #pragma unroll
    for (int i = 0; i < 4; i++) {
        #pragma unroll
        for (int j = 0; j < 4; j++) {
            int n = (n0t + j) * 16 + col;
            if (n < kN) {
                #pragma unroll
                for (int reg = 0; reg < 4; reg++) {
                    int brow = (m0t + i) * 16 + rbase + reg;
                    out[O_VERTS + (size_t)brow * kN + n] = acc[i][j][reg];
                }
            }
        }
    }
}

// ---------------------------------------------------------------------------
// k_lbs: fused LBS apply + jfv partial accumulation.
// Grid (512 bpairs x 4 vchunks) = 2048 blocks.  __launch_bounds__(256,2)
// keeps the round-2 codegen (VGPR 112, zero scratch); VGPR 112 -> 4 waves/SIMD
// resident (4x112=448<=512), doubling round-2's occupancy without the
// round-3 register cap that spilled acc[2][51] (hbm 146MB -> 1.5GB).
// Per-chunk jfv partials atomicAdd into out[O_JFV] (zeroed by k_pose).
// ---------------------------------------------------------------------------
__global__ __launch_bounds__(256, 2) void k_lbs(
    const float* __restrict__ amb0,
    const float* __restrict__ amb1,
    const float* __restrict__ Jh,
    const float* __restrict__ wsA,
    const float* __restrict__ wsRoot,
    float* __restrict__ out)
{
    const float* W = amb0_is_weights(amb0) ? amb0 : amb1;

    int t = threadIdx.x;
    int b0 = blockIdx.x * 2;
    int v0 = blockIdx.y * kVCh;
    int vend = min(v0 + kVCh, kV);

    const float4v* A04 = (const float4v*)(wsA + (size_t)b0 * 288);  // uniform
    const float4v* A14 = A04 + 72;
    float r00 = wsRoot[(size_t)b0 * 3 + 0];
    float r01 = wsRoot[(size_t)b0 * 3 + 1];
    float r02 = wsRoot[(size_t)b0 * 3 + 2];
    float r10 = wsRoot[(size_t)b0 * 3 + 3];
    float r11 = wsRoot[(size_t)b0 * 3 + 4];
    float r12 = wsRoot[(size_t)b0 * 3 + 5];

    float acc[2][kH * 3];
    #pragma unroll
    for (int tb = 0; tb < 2; tb++)
        #pragma unroll
        for (int i = 0; i < kH * 3; i++) acc[tb][i] = 0.f;

    for (int v = v0 + t; v < vend; v += 256) {
        const float4v* Wv4 = (const float4v*)(W + (size_t)v * kJ);  // 16B-aligned
        float4v wv[6];
        #pragma unroll
        for (int q = 0; q < 6; q++) wv[q] = Wv4[q];

        float o[2][3];
        #pragma unroll
        for (int tb = 0; tb < 2; tb++) {
            const float4v* A4 = (tb == 0) ? A04 : A14;
            float T0[4] = {0.f, 0.f, 0.f, 0.f};
            float T1[4] = {0.f, 0.f, 0.f, 0.f};
            float T2[4] = {0.f, 0.f, 0.f, 0.f};
            #pragma unroll
            for (int j = 0; j < kJ; j++) {
                float wj = wv[j >> 2][j & 3];
                float4v a0 = A4[j * 3 + 0];
                float4v a1 = A4[j * 3 + 1];
                float4v a2 = A4[j * 3 + 2];
                #pragma unroll
                for (int q = 0; q < 4; q++) {
                    T0[q] += wj * a0[q];
                    T1[q] += wj * a1[q];
                    T2[q] += wj * a2[q];
                }
            }
            float rr0 = (tb == 0) ? r00 : r10;
            float rr1 = (tb == 0) ? r01 : r11;
            float rr2 = (tb == 0) ? r02 : r12;
            float* op = out + O_VERTS + ((size_t)(b0 + tb) * kV + v) * 3;
            float x = op[0], y = op[1], z = op[2];
            float o0 = T0[0] * x + T0[1] * y + T0[2] * z + T0[3] - rr0;
            float o1 = T1[0] * x + T1[1] * y + T1[2] * z + T1[3] - rr1;
            float o2 = T2[0] * x + T2[1] * y + T2[2] * z + T2[3] - rr2;
            op[0] = o0;
            op[1] = o1;
            op[2] = o2;
            o[tb][0] = o0; o[tb][1] = o1; o[tb][2] = o2;
        }
        // jfv accumulation (Jh is j-major -> coalesced dword loads)
        #pragma unroll
        for (int j = 0; j < kH; j++) {
            float wj = Jh[(size_t)j * kV + v];
            #pragma unroll
            for (int tb = 0; tb < 2; tb++) {
                acc[tb][j * 3 + 0] += wj * o[tb][0];
                acc[tb][j * 3 + 1] += wj * o[tb][1];
                acc[tb][j * 3 + 2] += wj * o[tb][2];
            }
        }
    }

    // reduce 2x51 partials: wave shuffle -> LDS cross-wave -> atomic into out
    #pragma unroll
    for (int off = 32; off > 0; off >>= 1) {
        #pragma unroll
        for (int tb = 0; tb < 2; tb++)
            #pragma unroll
            for (int i = 0; i < kH * 3; i++)
                acc[tb][i] += __shfl_down(acc[tb][i], off, 64);
    }
    __shared__ float red[4][2 * kH * 3];
    int lane = t & 63, wave = t >> 6;
    if (lane == 0) {
        #pragma unroll
        for (int tb = 0; tb < 2; tb++)
            #pragma unroll
            for (int i = 0; i < kH * 3; i++)
                red[wave][tb * (kH * 3) + i] = acc[tb][i];
    }
    __syncthreads();
    if (t < 2 * kH * 3) {
        float s = red[0][t] + red[1][t] + red[2][t] + red[3][t];
        int tb = t / (kH * 3);
        int i = t - tb * (kH * 3);
        atomicAdd(&out[O_JFV + (size_t)(b0 + tb) * 51 + i], s);
    }
}

// ---------------------------------------------------------------------------
// k_fin: in-place root17 subtraction on the accumulated jfv sums.
// S = Jh @ (verts - root) = jfv - root (Jh rows sum to 1);
// out = S_i - S_{i%3} = jfv_i - jfv_{0,k} = jfv - root17.   One wave per b.
// ---------------------------------------------------------------------------
__global__ __launch_bounds__(64) void k_fin(float* __restrict__ out)
{
    int b = blockIdx.x;
    int t = threadIdx.x;
    float si = 0.f, sk = 0.f;
    if (t < 51) {
        si = out[O_JFV + (size_t)b * 51 + t];
        sk = out[O_JFV + (size_t)b * 51 + (t % 3)];
    }
    __syncthreads();
    if (t < 51) out[O_JFV + (size_t)b * 51 + t] = si - sk;
}

extern "C" void kernel_launch(void* const* d_in, const int* in_sizes, int n_in,
                              void* d_out, int out_size, void* d_ws, size_t ws_size,
                              hipStream_t stream) {
    const float *pose = nullptr, *betas = nullptr, *gor = nullptr, *vt = nullptr,
                *sd = nullptr, *pd = nullptr, *Jh = nullptr;
    const float *amb0 = nullptr, *amb1 = nullptr;
    for (int i = 0; i < n_in; i++) {
        const float* p = (const float*)d_in[i];
        switch (in_sizes[i]) {
            case 70656:   pose  = p; break;
            case 10240:   betas = p; break;
            case 3072:    gor   = p; break;
            case 20670:   vt    = p; break;
            case 206700:  sd    = p; break;
            case 4278690: pd    = p; break;
            case 117130:  Jh    = p; break;
            case 165360:  if (!amb0) amb0 = p; else amb1 = p; break;
            default: break;
        }
    }

    float* ws = (float*)d_ws;
    float* jsp     = ws + WS_JSP;
    float* wsA     = ws + WS_A;
    float* wsRoot  = ws + WS_ROOT;
    unsigned short* aswz = (unsigned short*)(ws + WS_ASWZ);
    unsigned short* bswz = (unsigned short*)(ws + WS_BSWZ);

    float* out = (float*)d_out;

    k_sfb  <<<dim3(kJsBlocks + kPbBlocks), dim3(256), 0, stream>>>(
        amb0, amb1, sd, vt, pd, jsp, bswz);
    k_pose <<<dim3(kB),                 dim3(64),  0, stream>>>(
        pose, betas, gor, jsp, wsA, wsRoot, aswz, out);
    k_gemm <<<dim3(kNT / 8, kB / 128),  dim3(256), 0, stream>>>(aswz, bswz, out);
    k_lbs  <<<dim3(kB / 2, kNVC),       dim3(256), 0, stream>>>(
        amb0, amb1, Jh, wsA, wsRoot, out);
    k_fin  <<<dim3(kB),                 dim3(64),  0, stream>>>(out);
}

// Round 5
// 287.806 us; speedup vs baseline: 2.1936x; 1.7632x over previous
//
#include <hip/hip_runtime.h>
#include <hip/hip_bf16.h>

// Problem constants
constexpr int kB  = 1024;
constexpr int kV  = 6890;
constexpr int kJ  = 24;
constexpr int kNB = 10;
constexpr int kP  = 207;   // 23*9
constexpr int kH  = 17;

constexpr int kN   = kV * 3;      // 20670
constexpr int kKP  = 224;         // K padded: 207 pf + 10 betas + 1 vt + 6 zero
constexpr int kNT  = 1296;        // n-tiles of 16 (N_pad = 20736)
constexpr int kNP  = kNT * 16;    // 20736
constexpr int kVC  = 862;         // v-chunk for k_js part (8 chunks)
constexpr int kTB  = 8;           // batch tile in k_lbs

constexpr int kJsBlocks = kJ * 8;         // 192
constexpr int kPbBlocks = kNP / 64;       // 324
constexpr int kVB = (kV + 255) / 256;     // 27 vertex blocks

// Output layout (flat concat, FP32 elements)
constexpr size_t O_VERTS  = 0;
constexpr size_t O_JOINTS = (size_t)kB * kV * 3;              // 21166080
constexpr size_t O_ROT    = O_JOINTS + (size_t)kB * kJ * 3;   // 21239808
constexpr size_t O_JFV    = O_ROT + (size_t)kB * kJ * 9;      // 21460992

// Workspace layout (fp32 element offsets). Total ~11 MB.
constexpr size_t WS_JSP  = 0;                        // 24*8*33 = 6336 floats
constexpr size_t WS_A    = 8192;                     // kB*288  = 294912
constexpr size_t WS_ROOT = WS_A + (size_t)kB * 288;  // kB*3 (padded to 4096)
constexpr size_t WS_ASWZ = WS_ROOT + 4096;           // 1024*224 ushort = 114688 floats
constexpr size_t WS_BSWZ = WS_ASWZ + 114688;         // 1296*7*512 ushort

typedef __attribute__((ext_vector_type(8))) short short8;
typedef __attribute__((ext_vector_type(4))) float float4v;

__device__ __forceinline__ unsigned short f2bf(float f) {
    unsigned u = __float_as_uint(f);
    unsigned r = (u + 0x7FFFu + ((u >> 16) & 1u)) >> 16;  // RNE
    return (unsigned short)r;
}

// inline classifier: amb0 is lbs_weights iff its first 24 floats (one weight
// row) sum to ~1.  J_regressor's first 24 entries sum to ~0.003.
__device__ __forceinline__ bool amb0_is_weights(const float* __restrict__ amb0) {
    float s = 0.f;
    #pragma unroll
    for (int i = 0; i < kJ; i++) s += amb0[i];
    return fabsf(s - 1.0f) < 0.5f;
}

// swizzled-A element index for (batch b, k-row k); must match k_gemm's read:
// lane l of tile kt reads shorts [l*8 .. l*8+7] = (quad=l>>4, minr=l&15, kin=0..7)
__device__ __forceinline__ size_t a_idx(int mtile, int minr, int k) {
    int kt = k >> 5, quad = (k >> 3) & 3, kin = k & 7;
    return ((size_t)(mtile * 7 + kt)) * 512 + (size_t)(quad * 128 + minr * 8 + kin);
}

// ---------------------------------------------------------------------------
// k_sfb: fused front-end (independent work, one dispatch).
//   blocks [0, 192):    js partials  partial[(j*8+c)*33 + i] over v-chunk c
//   blocks [192, 516):  swizzled bf16 B (K_pad=224 x N_pad=20736)
// ---------------------------------------------------------------------------
__global__ __launch_bounds__(256) void k_sfb(
    const float* __restrict__ amb0,
    const float* __restrict__ amb1,
    const float* __restrict__ sd,
    const float* __restrict__ vt,
    const float* __restrict__ pd,
    float* __restrict__ partial,
    unsigned short* __restrict__ bswz)
{
    __shared__ unsigned short lds[kKP][68];
    __shared__ float red[4][33];

    int t = threadIdx.x;

    if (blockIdx.x < kJsBlocks) {
        // ----- js part -----
        const float* Jreg = amb0_is_weights(amb0) ? amb1 : amb0;
        int j = blockIdx.x >> 3;
        int c = blockIdx.x & 7;
        int lane = t & 63;
        int wave = t >> 6;

        float acc[33];
        #pragma unroll
        for (int i = 0; i < 33; i++) acc[i] = 0.f;

        int vend = min(kVC * (c + 1), kV);
        for (int v = kVC * c + t; v < vend; v += 256) {
            float w = Jreg[j * kV + v];
            const float* sdp = sd + (size_t)v * 30;
            #pragma unroll
            for (int k = 0; k < 3; k++) {
                #pragma unroll
                for (int l = 0; l < kNB; l++)
                    acc[k * 11 + l] += w * sdp[k * 10 + l];
                acc[k * 11 + 10] += w * vt[v * 3 + k];
            }
        }
        #pragma unroll
        for (int off = 32; off > 0; off >>= 1) {
            #pragma unroll
            for (int i = 0; i < 33; i++)
                acc[i] += __shfl_down(acc[i], off, 64);
        }
        if (lane == 0) {
            #pragma unroll
            for (int i = 0; i < 33; i++) red[wave][i] = acc[i];
        }
        __syncthreads();
        if (t < 33) {
            float s = red[0][t] + red[1][t] + red[2][t] + red[3][t];
            partial[((size_t)j * 8 + c) * 33 + t] = s;
        }
    } else {
        // ----- prep_b part -----
        int g = blockIdx.x - kJsBlocks;
        int n0 = g * 64;

        for (int kbase = 0; kbase < kKP; kbase += 4) {
            int k = kbase + (t >> 6);
            int nl = t & 63;
            int n = n0 + nl;
            float val = 0.f;
            if (n < kN) {
                if (k < kP)                 val = pd[(size_t)k * kN + n];
                else if (k < kP + kNB)      val = sd[(size_t)n * kNB + (k - kP)];
                else if (k == kP + kNB)     val = vt[n];
            }
            lds[k][nl] = f2bf(val);
        }
        __syncthreads();

        #pragma unroll 1
        for (int tt = 0; tt < 4; tt++) {
            int ntile = g * 4 + tt;
            #pragma unroll 1
            for (int kt = 0; kt < 7; kt++) {
                size_t base = ((size_t)ntile * 7 + kt) * 512;
                #pragma unroll
                for (int u = 0; u < 2; u++) {
                    int e = t * 2 + u;
                    int quad = e >> 7, rem = e & 127;
                    int nin = rem >> 3, kin = rem & 7;
                    int k = kt * 32 + quad * 8 + kin;
                    bswz[base + e] = lds[k][tt * 16 + nin];
                }
            }
        }
    }
}

// ---------------------------------------------------------------------------
// k_pose: per-batch rodrigues + FK chain + A matrices.
// ---------------------------------------------------------------------------
__global__ __launch_bounds__(64) void k_pose(
    const float* __restrict__ pose,
    const float* __restrict__ betas,
    const float* __restrict__ gor,
    const float* __restrict__ jsp,
    float* __restrict__ wsA,
    float* __restrict__ wsRoot,
    unsigned short* __restrict__ aswz,
    float* __restrict__ out)
{
    __shared__ float Rsh[kJ][9];
    __shared__ float Jr[kJ][3];
    __shared__ float G[kJ][12];

    int b = blockIdx.x;
    int t = threadIdx.x;
    int mtile = b >> 4, minr = b & 15;

    if (t < kJ) {
        float rx, ry, rz;
        if (t == 0) {
            rx = gor[b * 3 + 0]; ry = gor[b * 3 + 1]; rz = gor[b * 3 + 2];
        } else {
            int o = b * 69 + (t - 1) * 3;
            rx = pose[o]; ry = pose[o + 1]; rz = pose[o + 2];
        }
        float ex = rx + 1e-8f, ey = ry + 1e-8f, ez = rz + 1e-8f;
        float ang = sqrtf(ex * ex + ey * ey + ez * ez);
        float x = rx / ang, y = ry / ang, z = rz / ang;
        float s = sinf(ang), c = cosf(ang), oc = 1.0f - c;
        float r[9];
        r[0] = 1.0f - oc * (y * y + z * z);
        r[1] = -s * z + oc * (x * y);
        r[2] =  s * y + oc * (x * z);
        r[3] =  s * z + oc * (x * y);
        r[4] = 1.0f - oc * (x * x + z * z);
        r[5] = -s * x + oc * (y * z);
        r[6] = -s * y + oc * (x * z);
        r[7] =  s * x + oc * (y * z);
        r[8] = 1.0f - oc * (x * x + y * y);
        #pragma unroll
        for (int i = 0; i < 9; i++) Rsh[t][i] = r[i];
        float* ro = out + O_ROT + (size_t)b * (kJ * 9) + (size_t)t * 9;
        #pragma unroll
        for (int i = 0; i < 9; i++) ro[i] = r[i];
        if (t >= 1) {
            // pose-feature rows 0..206 of swizzled A, bf16
            #pragma unroll
            for (int i = 0; i < 9; i++) {
                int k = (t - 1) * 9 + i;
                float val = r[i] - ((i == 0 || i == 4 || i == 8) ? 1.0f : 0.0f);
                aswz[a_idx(mtile, minr, k)] = f2bf(val);
            }
        }
        // Jr = (reduced js partials) dot [betas | 1]
        float bt[kNB];
        #pragma unroll
        for (int l = 0; l < kNB; l++) bt[l] = betas[b * kNB + l];
        #pragma unroll
        for (int k2 = 0; k2 < 3; k2++) {
            float row[11];
            #pragma unroll
            for (int i = 0; i < 11; i++) row[i] = 0.f;
            #pragma unroll
            for (int c8 = 0; c8 < 8; c8++) {
                const float* pp = jsp + ((size_t)t * 8 + c8) * 33 + k2 * 11;
                #pragma unroll
                for (int i = 0; i < 11; i++) row[i] += pp[i];
            }
            float acc = row[10];
            #pragma unroll
            for (int l = 0; l < kNB; l++) acc += bt[l] * row[l];
            Jr[t][k2] = acc;
        }
    } else if (t < 41 + kJ) {
        // rows 207..223 of swizzled A: betas | 1.0 | zero pad (17 rows)
        int idx = t - kJ;
        if (idx < 17) {
            int k = kP + idx;
            float val = 0.f;
            if (idx < kNB)          val = betas[b * kNB + idx];
            else if (k == kP + kNB) val = 1.0f;
            aswz[a_idx(mtile, minr, k)] = f2bf(val);
        }
    }
    __syncthreads();

    if (t == 0) {
        const int par[kJ] = {-1,0,0,0,1,2,3,4,5,6,7,8,9,9,9,12,13,14,16,17,18,19,20,21};
        #pragma unroll
        for (int m = 0; m < 3; m++) {
            #pragma unroll
            for (int n = 0; n < 3; n++) G[0][m * 4 + n] = Rsh[0][m * 3 + n];
            G[0][m * 4 + 3] = Jr[0][m];
        }
        for (int i = 1; i < kJ; i++) {
            int p = par[i];
            float rel[3];
            #pragma unroll
            for (int k = 0; k < 3; k++) rel[k] = Jr[i][k] - Jr[p][k];
            #pragma unroll
            for (int m = 0; m < 3; m++) {
                float g0 = G[p][m * 4 + 0], g1 = G[p][m * 4 + 1], g2 = G[p][m * 4 + 2];
                #pragma unroll
                for (int n = 0; n < 3; n++) {
                    G[i][m * 4 + n] = g0 * Rsh[i][0 * 3 + n]
                                    + g1 * Rsh[i][1 * 3 + n]
                                    + g2 * Rsh[i][2 * 3 + n];
                }
                G[i][m * 4 + 3] = g0 * rel[0] + g1 * rel[1] + g2 * rel[2]
                                + G[p][m * 4 + 3];
            }
        }
    }
    __syncthreads();

    if (t < kJ) {
        float* Aj = wsA + (size_t)b * 288 + (size_t)t * 12;
        float* jo = out + O_JOINTS + (size_t)b * (kJ * 3) + (size_t)t * 3;
        #pragma unroll
        for (int m = 0; m < 3; m++) {
            float g0 = G[t][m * 4 + 0], g1 = G[t][m * 4 + 1], g2 = G[t][m * 4 + 2];
            Aj[m * 4 + 0] = g0;
            Aj[m * 4 + 1] = g1;
            Aj[m * 4 + 2] = g2;
            Aj[m * 4 + 3] = G[t][m * 4 + 3]
                          - (g0 * Jr[t][0] + g1 * Jr[t][1] + g2 * Jr[t][2]);
            jo[m] = G[t][m * 4 + 3] - G[0][m * 4 + 3];
        }
        if (t == 0) {
            #pragma unroll
            for (int k = 0; k < 3; k++) wsRoot[b * 3 + k] = G[0][k * 4 + 3];
        }
    }
}

// ---------------------------------------------------------------------------
// k_gemm: v_posed[b][n] = A(1024x224) @ B(224x20670) -> out[O_VERTS] (fp32).
// ---------------------------------------------------------------------------
__global__ __launch_bounds__(256) void k_gemm(
    const unsigned short* __restrict__ A,
    const unsigned short* __restrict__ B,
    float* __restrict__ out)
{
    int tid = threadIdx.x;
    int lane = tid & 63;
    int wid = tid >> 6;
    int m0t = blockIdx.y * 8 + (wid >> 1) * 4;
    int n0t = blockIdx.x * 8 + (wid & 1) * 4;

    float4v acc[4][4];
    #pragma unroll
    for (int i = 0; i < 4; i++)
        #pragma unroll
        for (int j = 0; j < 4; j++)
            acc[i][j] = (float4v){0.f, 0.f, 0.f, 0.f};

    #pragma unroll
    for (int kt = 0; kt < 7; kt++) {
        short8 a[4], b[4];
        #pragma unroll
        for (int i = 0; i < 4; i++)
            a[i] = *(const short8*)(A + ((size_t)(m0t + i) * 7 + kt) * 512 + lane * 8);
        #pragma unroll
        for (int j = 0; j < 4; j++)
            b[j] = *(const short8*)(B + ((size_t)(n0t + j) * 7 + kt) * 512 + lane * 8);
        #pragma unroll
        for (int i = 0; i < 4; i++)
            #pragma unroll
            for (int j = 0; j < 4; j++)
                acc[i][j] = __builtin_amdgcn_mfma_f32_16x16x32_bf16(
                    a[i], b[j], acc[i][j], 0, 0, 0);
    }

    int rbase = (lane >> 4) * 4;
    int col = lane & 15;
    #pragma unroll
    for (int i = 0; i < 4; i++) {
        #pragma unroll
        for (int j = 0; j < 4; j++) {
            int n = (n0t + j) * 16 + col;
            if (n < kN) {
                #pragma unroll
                for (int reg = 0; reg < 4; reg++) {
                    int brow = (m0t + i) * 16 + rbase + reg;
                    out[O_VERTS + (size_t)brow * kN + n] = acc[i][j][reg];
                }
            }
        }
    }
}

// ---------------------------------------------------------------------------
// k_lbs: verts only (jfv de-fused -- r4's acc[2][51] pinned 112 VGPR, forced
// a 612-shuffle reduce per block, and occupancy never rose; the verts-only
// body carries ~60-80 live floats).  TB=8 batch-tile: w[24] amortized over 8
// batches; per-batch T built from wave-uniform s_loads (1 dwordx4 : 8 FMAs).
// Grid 27 x 128 = 3456 blocks.
// ---------------------------------------------------------------------------
__global__ __launch_bounds__(256, 4) void k_lbs(
    const float* __restrict__ amb0,
    const float* __restrict__ amb1,
    const float* __restrict__ wsA,
    const float* __restrict__ wsRoot,
    float* __restrict__ out)
{
    const float* W = amb0_is_weights(amb0) ? amb0 : amb1;

    int t = threadIdx.x;
    int v = blockIdx.x * 256 + t;
    int b0 = blockIdx.y * kTB;
    bool active = (v < kV);
    int vc = active ? v : (kV - 1);

    float w[kJ];
    {
        const float4v* Wv4 = (const float4v*)(W + (size_t)vc * kJ);  // 16B-aligned
        #pragma unroll
        for (int q = 0; q < 6; q++) {
            float4v x = Wv4[q];
            w[q * 4 + 0] = x[0]; w[q * 4 + 1] = x[1];
            w[q * 4 + 2] = x[2]; w[q * 4 + 3] = x[3];
        }
    }

    #pragma unroll 1
    for (int tb = 0; tb < kTB; tb++) {
        int b = b0 + tb;
        const float4v* A4 = (const float4v*)(wsA + (size_t)b * 288);  // uniform
        float T0[4] = {0.f, 0.f, 0.f, 0.f};
        float T1[4] = {0.f, 0.f, 0.f, 0.f};
        float T2[4] = {0.f, 0.f, 0.f, 0.f};
        #pragma unroll
        for (int j = 0; j < kJ; j++) {
            float wj = w[j];
            float4v a0 = A4[j * 3 + 0];
            float4v a1 = A4[j * 3 + 1];
            float4v a2 = A4[j * 3 + 2];
            #pragma unroll
            for (int q = 0; q < 4; q++) {
                T0[q] += wj * a0[q];
                T1[q] += wj * a1[q];
                T2[q] += wj * a2[q];
            }
        }
        float r0 = wsRoot[(size_t)b * 3 + 0];   // uniform
        float r1 = wsRoot[(size_t)b * 3 + 1];
        float r2 = wsRoot[(size_t)b * 3 + 2];
        if (active) {
            float* op = out + O_VERTS + ((size_t)b * kV + v) * 3;
            float x = op[0], y = op[1], z = op[2];
            op[0] = T0[0] * x + T0[1] * y + T0[2] * z + T0[3] - r0;
            op[1] = T1[0] * x + T1[1] * y + T1[2] * z + T1[3] - r1;
            op[2] = T2[0] * x + T2[1] * y + T2[2] * z + T2[3] - r2;
        }
    }
}

// ---------------------------------------------------------------------------
// k_jfv: jfv[b] = Jh @ verts[b], root17 subtraction folded in-block.
// One block per batch; verts re-read (85 MB ~ 14us HBM floor); Jh L2-resident.
// ---------------------------------------------------------------------------
__global__ __launch_bounds__(256) void k_jfv(
    const float* __restrict__ Jh,
    const float* __restrict__ verts,
    float* __restrict__ out)
{
    int b = blockIdx.x;
    int t = threadIdx.x;
    int lane = t & 63, wave = t >> 6;

    float acc[kH * 3];
    #pragma unroll
    for (int i = 0; i < kH * 3; i++) acc[i] = 0.f;

    for (int v = t; v < kV; v += 256) {
        const float* vp = verts + ((size_t)b * kV + v) * 3;
        float vx = vp[0], vy = vp[1], vz = vp[2];
        #pragma unroll
        for (int j = 0; j < kH; j++) {
            float wj = Jh[(size_t)j * kV + v];
            acc[j * 3 + 0] += wj * vx;
            acc[j * 3 + 1] += wj * vy;
            acc[j * 3 + 2] += wj * vz;
        }
    }
    #pragma unroll
    for (int off = 32; off > 0; off >>= 1) {
        #pragma unroll
        for (int i = 0; i < kH * 3; i++)
            acc[i] += __shfl_down(acc[i], off, 64);
    }
    __shared__ float red[4][kH * 3];
    __shared__ float fin[kH * 3];
    if (lane == 0) {
        #pragma unroll
        for (int i = 0; i < kH * 3; i++) red[wave][i] = acc[i];
    }
    __syncthreads();
    if (t < kH * 3)
        fin[t] = red[0][t] + red[1][t] + red[2][t] + red[3][t];
    __syncthreads();
    if (t < kH * 3) {
        // verts already root-subtracted; subtracting the per-axis j'=0 sums
        // reproduces jfv - root17 exactly (Jh rows sum to 1)
        out[O_JFV + (size_t)b * 51 + t] = fin[t] - fin[t % 3];
    }
}

extern "C" void kernel_launch(void* const* d_in, const int* in_sizes, int n_in,
                              void* d_out, int out_size, void* d_ws, size_t ws_size,
                              hipStream_t stream) {
    const float *pose = nullptr, *betas = nullptr, *gor = nullptr, *vt = nullptr,
                *sd = nullptr, *pd = nullptr, *Jh = nullptr;
    const float *amb0 = nullptr, *amb1 = nullptr;
    for (int i = 0; i < n_in; i++) {
        const float* p = (const float*)d_in[i];
        switch (in_sizes[i]) {
            case 70656:   pose  = p; break;
            case 10240:   betas = p; break;
            case 3072:    gor   = p; break;
            case 20670:   vt    = p; break;
            case 206700:  sd    = p; break;
            case 4278690: pd    = p; break;
            case 117130:  Jh    = p; break;
            case 165360:  if (!amb0) amb0 = p; else amb1 = p; break;
            default: break;
        }
    }

    float* ws = (float*)d_ws;
    float* jsp     = ws + WS_JSP;
    float* wsA     = ws + WS_A;
    float* wsRoot  = ws + WS_ROOT;
    unsigned short* aswz = (unsigned short*)(ws + WS_ASWZ);
    unsigned short* bswz = (unsigned short*)(ws + WS_BSWZ);

    float* out = (float*)d_out;

    k_sfb  <<<dim3(kJsBlocks + kPbBlocks), dim3(256), 0, stream>>>(
        amb0, amb1, sd, vt, pd, jsp, bswz);
    k_pose <<<dim3(kB),                 dim3(64),  0, stream>>>(
        pose, betas, gor, jsp, wsA, wsRoot, aswz, out);
    k_gemm <<<dim3(kNT / 8, kB / 128),  dim3(256), 0, stream>>>(aswz, bswz, out);
    k_lbs  <<<dim3(kVB, kB / kTB),      dim3(256), 0, stream>>>(
        amb0, amb1, wsA, wsRoot, out);
    k_jfv  <<<dim3(kB),                 dim3(256), 0, stream>>>(
        Jh, out + O_VERTS, out);
}